// Round 1
// baseline (337.581 us; speedup 1.0000x reference)
//
#include <hip/hip_runtime.h>

#define KP 32
#define NQg 16384
#define CD 512
#define HC 256
#define NS 3

// ---------------- init: refined = prototypes, wsum = 0 ----------------
__global__ void k_init(const float* __restrict__ proto, float* __restrict__ refined,
                       float* __restrict__ wsum) {
    int idx = blockIdx.x * 256 + threadIdx.x;
    if (idx < KP * CD) refined[idx] = proto[idx];
    if (idx < NS * KP) wsum[idx] = 0.f;
}

// ---------------- softmax over K=32 per query, 3 temperatures ----------------
__global__ __launch_bounds__(256) void k_soft(const float* __restrict__ qd,
                                              float* __restrict__ soft_all) {
    int q = blockIdx.x * 256 + threadIdx.x;
    float d[32];
    const float4* p = (const float4*)(qd + (size_t)q * 32);
#pragma unroll
    for (int j = 0; j < 8; j++) {
        float4 v = p[j];
        d[4 * j] = v.x; d[4 * j + 1] = v.y; d[4 * j + 2] = v.z; d[4 * j + 3] = v.w;
    }
#pragma unroll
    for (int s = 0; s < 3; s++) {
        float inv = -1.0f / (float)(s + 1);
        float e[32];
        float sum = 0.f;
#pragma unroll
        for (int k = 0; k < 32; k++) { e[k] = __expf(d[k] * inv); sum += e[k]; }
        float r = 1.0f / sum;
        float4* o = (float4*)(soft_all + (size_t)s * NQg * 32 + (size_t)q * 32);
#pragma unroll
        for (int j = 0; j < 8; j++)
            o[j] = make_float4(e[4 * j] * r, e[4 * j + 1] * r, e[4 * j + 2] * r, e[4 * j + 3] * r);
    }
}

// ---------------- wsum[s][k] = sum_q soft ----------------
__global__ void k_wsum(const float* __restrict__ soft_all, float* __restrict__ wsum) {
    __shared__ float red[256];
    int s = blockIdx.x / 16, slice = blockIdx.x % 16;
    size_t base = (size_t)s * NQg * 32 + (size_t)slice * 1024 * 32;
    float local = 0.f;
    for (int j = 0; j < 128; j++) local += soft_all[base + (size_t)j * 256 + threadIdx.x];
    red[threadIdx.x] = local;
    __syncthreads();
    if (threadIdx.x < 32) {
        float t = 0.f;
#pragma unroll
        for (int i = 0; i < 8; i++) t += red[threadIdx.x + 32 * i];
        atomicAdd(&wsum[s * 32 + threadIdx.x], t);
    }
}

// ---------------- split-K GEMM: part[qc][sk][c] partial of soft^T @ qf ----------------
// grid 512 = 64 q-chunks x 2 sk-tiles(64) x 4 c-tiles(128); block tile 64sk x 128c
__global__ __launch_bounds__(256) void k_acc(const float* __restrict__ soft_all,
                                             const float* __restrict__ qf,
                                             float* __restrict__ part) {
    __shared__ float soft_lds[16 * 64];
    __shared__ float qf_lds[16 * 128];
    int bid = blockIdx.x;
    int bq = bid >> 3;
    int rem = bid & 7;
    int sk0 = (rem & 1) * 64;
    int c0 = (rem >> 1) * 128;
    int q0 = bq * 256;
    int tid = threadIdx.x;
    int w = tid >> 6, lane = tid & 63;
    int wsk = (w & 1) * 32;
    int wc = (w >> 1) * 64;
    int lsk = (lane & 3) * 8;
    int lc = (lane >> 2) * 4;
    float acc[8][4];
#pragma unroll
    for (int i = 0; i < 8; i++)
#pragma unroll
        for (int j = 0; j < 4; j++) acc[i][j] = 0.f;

    for (int qb = 0; qb < 16; qb++) {
        int qbase = q0 + qb * 16;
#pragma unroll
        for (int i = 0; i < 4; i++) {
            int idx = i * 256 + tid;
            int j = idx >> 6, t = idx & 63;
            int skg = sk0 + t;
            float v = 0.f;
            if (skg < 96)
                v = soft_all[(size_t)(skg >> 5) * NQg * 32 + (size_t)(qbase + j) * 32 + (skg & 31)];
            soft_lds[j * 64 + t] = v;
        }
#pragma unroll
        for (int i = 0; i < 8; i++) {
            int idx = i * 256 + tid;
            int j = idx >> 7, t = idx & 127;
            qf_lds[j * 128 + t] = qf[(size_t)(qbase + j) * 512 + c0 + t];
        }
        __syncthreads();
#pragma unroll
        for (int j = 0; j < 16; j++) {
            float4 qv = *(float4*)&qf_lds[j * 128 + wc + lc];
            float4 s0 = *(float4*)&soft_lds[j * 64 + wsk + lsk];
            float4 s1 = *(float4*)&soft_lds[j * 64 + wsk + lsk + 4];
            float sv[8] = {s0.x, s0.y, s0.z, s0.w, s1.x, s1.y, s1.z, s1.w};
#pragma unroll
            for (int i = 0; i < 8; i++) {
                acc[i][0] += sv[i] * qv.x;
                acc[i][1] += sv[i] * qv.y;
                acc[i][2] += sv[i] * qv.z;
                acc[i][3] += sv[i] * qv.w;
            }
        }
        __syncthreads();
    }
    int cpos = c0 + wc + lc;
#pragma unroll
    for (int i = 0; i < 8; i++) {
        int sk = sk0 + wsk + lsk + i;
        if (sk < 96) {
            float4 v = make_float4(acc[i][0], acc[i][1], acc[i][2], acc[i][3]);
            *(float4*)&part[((size_t)bq * 96 + sk) * 512 + cpos] = v;
        }
    }
}

// ---------------- reduce partials -> wmean[sk][c] ----------------
__global__ void k_reduce(const float* __restrict__ part, const float* __restrict__ wsum,
                         float* __restrict__ wmean) {
    int idx = blockIdx.x * 256 + threadIdx.x;  // < 96*512
    float s = 0.f;
#pragma unroll 8
    for (int bq = 0; bq < 64; bq++) s += part[(size_t)bq * 49152 + idx];
    int sk = idx >> 9;
    wmean[idx] = s / fmaxf(wsum[sk], 1e-6f);
}

// ---------------- MLP layer 1: hbuf += partial of concat @ W1 (+b1) ----------------
// grid 128 = 32 rows x 4 K-slices; relu deferred to mlp2
__global__ void k_mlp1(const float* __restrict__ refined, const float* __restrict__ wmean,
                       const float* __restrict__ W1, const float* __restrict__ b1,
                       float* __restrict__ hbuf, int s) {
    __shared__ float crow[256];
    int r = blockIdx.x >> 2, ks = blockIdx.x & 3;
    int t = threadIdx.x;
    int i0 = ks * 256;
    int gi = i0 + t;
    crow[t] = (gi < 512) ? refined[r * 512 + gi] : wmean[(s * 32 + r) * 512 + (gi - 512)];
    __syncthreads();
    int c = t, c2 = t + 256;
    float a0 = (ks == 0) ? b1[c] : 0.f;
    float a1 = (ks == 0) ? b1[c2] : 0.f;
    for (int ii = 0; ii < 256; ii++) {
        float cv = crow[ii];
        const float* wrow = W1 + (size_t)(i0 + ii) * 512;
        a0 += cv * wrow[c];
        a1 += cv * wrow[c2];
    }
    atomicAdd(&hbuf[r * 512 + c], a0);
    atomicAdd(&hbuf[r * 512 + c2], a1);
}

// ---------------- MLP layer 2: refined += 0.1*(relu(h) @ W2 + b2) ----------------
// grid 64 = 32 rows x 2 K-slices
__global__ void k_mlp2(const float* __restrict__ hbuf, const float* __restrict__ W2,
                       const float* __restrict__ b2, float* __restrict__ refined) {
    __shared__ float hrow[256];
    int r = blockIdx.x >> 1, ks = blockIdx.x & 1;
    int t = threadIdx.x;
    int i0 = ks * 256;
    hrow[t] = fmaxf(hbuf[r * 512 + i0 + t], 0.f);
    __syncthreads();
    int c = t, c2 = t + 256;
    float a0 = (ks == 0) ? b2[c] : 0.f;
    float a1 = (ks == 0) ? b2[c2] : 0.f;
    for (int ii = 0; ii < 256; ii++) {
        float hv = hrow[ii];
        const float* wrow = W2 + (size_t)(i0 + ii) * 512;
        a0 += hv * wrow[c];
        a1 += hv * wrow[c2];
    }
    atomicAdd(&refined[r * 512 + c], 0.1f * a0);
    atomicAdd(&refined[r * 512 + c2], 0.1f * a1);
}

// ---------------- copy refined -> d_out ----------------
__global__ void k_out(const float* __restrict__ refined, float* __restrict__ dout) {
    int idx = blockIdx.x * 256 + threadIdx.x;
    dout[idx] = refined[idx];
}

// ---------------- hpb[k][h] = prototypes @ Wp + bc1 ----------------
__global__ void k_hpb(const float* __restrict__ proto, const float* __restrict__ Wc1,
                      const float* __restrict__ bc1, float* __restrict__ hpb) {
    int r = blockIdx.x;
    int c = threadIdx.x;
    float a = bc1[c];
    for (int i = 0; i < 512; i++) a += proto[r * 512 + i] * Wc1[(size_t)i * 256 + c];
    hpb[r * 256 + c] = a;
}

// ---------------- fused hq GEMM + confidence reduction ----------------
// grid 512 blocks, 32 queries each. LDS union: [qf_t(32x36) + wq(32x256)] vs hq(32x260)
__global__ __launch_bounds__(256) void k_conf(const float* __restrict__ qf,
                                              const float* __restrict__ Wc1,
                                              const float* __restrict__ hpb,
                                              const float* __restrict__ Wc2,
                                              const float* __restrict__ bc2p,
                                              float* __restrict__ dout) {
    __shared__ float uA[9344];   // qft: [0,1152), wq: [1152, 1152+8192); hq aliases [0, 8320)
    __shared__ float wc2s[256];
    __shared__ float confl[32];
    float* qft = uA;
    float* wqs = uA + 1152;
    float* hq = uA;

    int tid = threadIdx.x;
    int lane = tid & 63;
    int w = tid >> 6;
    int q0 = blockIdx.x * 32;

    wc2s[tid] = Wc2[tid];
    if (tid < 32) confl[tid] = 0.f;

    int qoff4 = (lane & 7) * 4;          // 4 queries per thread
    int wc = w * 64;                     // wave c-slice
    int cg = (lane >> 3) * 8;            // 8 channels per thread
    float acc[4][8];
#pragma unroll
    for (int i = 0; i < 4; i++)
#pragma unroll
        for (int j = 0; j < 8; j++) acc[i][j] = 0.f;

    for (int kc = 0; kc < 512; kc += 32) {
        __syncthreads();  // protect LDS (also covers initial wc2s/confl writes)
#pragma unroll
        for (int i = 0; i < 4; i++) {
            int idx = i * 256 + tid;
            int q = idx >> 5, kk = idx & 31;
            qft[kk * 36 + q] = qf[(size_t)(q0 + q) * 512 + kc + kk];
        }
#pragma unroll
        for (int i = 0; i < 32; i++) {
            int idx = i * 256 + tid;
            int kk = idx >> 8, c = idx & 255;
            wqs[kk * 256 + c] = Wc1[(size_t)(512 + kc + kk) * 256 + c];
        }
        __syncthreads();
#pragma unroll
        for (int kk = 0; kk < 32; kk++) {
            float4 a0 = *(float4*)&qft[kk * 36 + qoff4];
            float4 b0 = *(float4*)&wqs[kk * 256 + wc + cg];
            float4 b1 = *(float4*)&wqs[kk * 256 + wc + cg + 4];
            float av[4] = {a0.x, a0.y, a0.z, a0.w};
#pragma unroll
            for (int qi = 0; qi < 4; qi++) {
                acc[qi][0] += av[qi] * b0.x; acc[qi][1] += av[qi] * b0.y;
                acc[qi][2] += av[qi] * b0.z; acc[qi][3] += av[qi] * b0.w;
                acc[qi][4] += av[qi] * b1.x; acc[qi][5] += av[qi] * b1.y;
                acc[qi][6] += av[qi] * b1.z; acc[qi][7] += av[qi] * b1.w;
            }
        }
    }
    __syncthreads();  // done reading qft/wqs; hq aliases this memory
#pragma unroll
    for (int qi = 0; qi < 4; qi++) {
        int q = qoff4 + qi;
        float4 v0 = make_float4(acc[qi][0], acc[qi][1], acc[qi][2], acc[qi][3]);
        float4 v1 = make_float4(acc[qi][4], acc[qi][5], acc[qi][6], acc[qi][7]);
        *(float4*)&hq[q * 260 + wc + cg] = v0;
        *(float4*)&hq[q * 260 + wc + cg + 4] = v1;
    }
    __syncthreads();

    // phase 2: per (k, q) confidence
    int k = tid >> 3;
    int qoff = tid & 7;
    float bc2 = bc2p[0];
    float s4[4] = {0.f, 0.f, 0.f, 0.f};
    for (int h = 0; h < 256; h += 4) {
        float4 pv = *(const float4*)&hpb[k * 256 + h];
        float4 wv = *(float4*)&wc2s[h];
#pragma unroll
        for (int j = 0; j < 4; j++) {
            float4 hv = *(float4*)&hq[(qoff + 8 * j) * 260 + h];
            s4[j] += fmaxf(pv.x + hv.x, 0.f) * wv.x;
            s4[j] += fmaxf(pv.y + hv.y, 0.f) * wv.y;
            s4[j] += fmaxf(pv.z + hv.z, 0.f) * wv.z;
            s4[j] += fmaxf(pv.w + hv.w, 0.f) * wv.w;
        }
    }
    float local = 0.f;
#pragma unroll
    for (int j = 0; j < 4; j++) local += 1.0f / (1.0f + __expf(-(s4[j] + bc2)));
    atomicAdd(&confl[k], local);
    __syncthreads();
    if (tid < 32) atomicAdd(&dout[16384 + tid], confl[tid] * (1.0f / 16384.0f));
}

extern "C" void kernel_launch(void* const* d_in, const int* in_sizes, int n_in,
                              void* d_out, int out_size, void* d_ws, size_t ws_size,
                              hipStream_t stream) {
    const float* proto = (const float*)d_in[0];
    const float* qf    = (const float*)d_in[1];
    const float* qd    = (const float*)d_in[2];
    const float* W1    = (const float*)d_in[3];
    const float* b1    = (const float*)d_in[4];
    const float* W2    = (const float*)d_in[5];
    const float* b2    = (const float*)d_in[6];
    const float* Wc1   = (const float*)d_in[7];
    const float* bc1   = (const float*)d_in[8];
    const float* Wc2   = (const float*)d_in[9];
    const float* bc2   = (const float*)d_in[10];
    float* out = (float*)d_out;

    float* ws = (float*)d_ws;
    float* soft_all = ws;                    // 3*16384*32 = 1,572,864
    float* part     = ws + 1572864;          // 64*96*512  = 3,145,728
    float* wsum     = ws + 4718592;          // 96
    float* wmean    = ws + 4718688;          // 49,152
    float* refined  = ws + 4767840;          // 16,384
    float* hbuf     = ws + 4784224;          // 16,384
    float* hpb      = ws + 4800608;          // 8,192

    hipMemsetAsync((char*)d_out + 16384 * sizeof(float), 0, 32 * sizeof(float), stream);
    k_init<<<64, 256, 0, stream>>>(proto, refined, wsum);
    k_soft<<<64, 256, 0, stream>>>(qd, soft_all);
    k_wsum<<<48, 256, 0, stream>>>(soft_all, wsum);
    k_acc<<<512, 256, 0, stream>>>(soft_all, qf, part);
    k_reduce<<<192, 256, 0, stream>>>(part, wsum, wmean);
    for (int s = 0; s < 3; s++) {
        hipMemsetAsync(hbuf, 0, 16384 * sizeof(float), stream);
        k_mlp1<<<128, 256, 0, stream>>>(refined, wmean, W1, b1, hbuf, s);
        k_mlp2<<<64, 256, 0, stream>>>(hbuf, W2, b2, refined);
    }
    k_out<<<64, 256, 0, stream>>>(refined, out);
    k_hpb<<<32, 256, 0, stream>>>(proto, Wc1, bc1, hpb);
    k_conf<<<512, 256, 0, stream>>>(qf, Wc1, hpb, Wc2, bc2, out);
}

// Round 2
// 301.524 us; speedup vs baseline: 1.1196x; 1.1196x over previous
//
#include <hip/hip_runtime.h>

#define KP 32
#define NQg 16384
#define CD 512
#define HC 256
#define NS 3

typedef __attribute__((ext_vector_type(8))) short short8;
typedef __attribute__((ext_vector_type(8))) __bf16 bf16x8;
typedef __attribute__((ext_vector_type(4))) float floatx4;

union S8B8 { short8 s; bf16x8 b; };

__device__ __forceinline__ short f2bf(float f) {
    union { float f; unsigned u; } v; v.f = f;
    unsigned r = v.u + 0x7fffu + ((v.u >> 16) & 1u);   // RNE
    return (short)(r >> 16);
}

// ---------------- init: refined = prototypes, wsum = 0 ----------------
__global__ void k_init(const float* __restrict__ proto, float* __restrict__ refined,
                       float* __restrict__ wsum) {
    int idx = blockIdx.x * 256 + threadIdx.x;
    if (idx < KP * CD) refined[idx] = proto[idx];
    if (idx < NS * KP) wsum[idx] = 0.f;
}

// ---------------- softmax over K=32 per query, 3 temperatures ----------------
__global__ __launch_bounds__(256) void k_soft(const float* __restrict__ qd,
                                              float* __restrict__ soft_all) {
    int q = blockIdx.x * 256 + threadIdx.x;
    float d[32];
    const float4* p = (const float4*)(qd + (size_t)q * 32);
#pragma unroll
    for (int j = 0; j < 8; j++) {
        float4 v = p[j];
        d[4 * j] = v.x; d[4 * j + 1] = v.y; d[4 * j + 2] = v.z; d[4 * j + 3] = v.w;
    }
#pragma unroll
    for (int s = 0; s < 3; s++) {
        float inv = -1.0f / (float)(s + 1);
        float e[32];
        float sum = 0.f;
#pragma unroll
        for (int k = 0; k < 32; k++) { e[k] = __expf(d[k] * inv); sum += e[k]; }
        float r = 1.0f / sum;
        float4* o = (float4*)(soft_all + (size_t)s * NQg * 32 + (size_t)q * 32);
#pragma unroll
        for (int j = 0; j < 8; j++)
            o[j] = make_float4(e[4 * j] * r, e[4 * j + 1] * r, e[4 * j + 2] * r, e[4 * j + 3] * r);
    }
}

// ---------------- wsum[s][k] = sum_q soft ----------------
__global__ void k_wsum(const float* __restrict__ soft_all, float* __restrict__ wsum) {
    __shared__ float red[256];
    int s = blockIdx.x / 16, slice = blockIdx.x % 16;
    size_t base = (size_t)s * NQg * 32 + (size_t)slice * 1024 * 32;
    float local = 0.f;
    for (int j = 0; j < 128; j++) local += soft_all[base + (size_t)j * 256 + threadIdx.x];
    red[threadIdx.x] = local;
    __syncthreads();
    if (threadIdx.x < 32) {
        float t = 0.f;
#pragma unroll
        for (int i = 0; i < 8; i++) t += red[threadIdx.x + 32 * i];
        atomicAdd(&wsum[s * 32 + threadIdx.x], t);
    }
}

// ---------------- split-K GEMM: part[qc][sk][c] partial of soft^T @ qf ----------------
__global__ __launch_bounds__(256) void k_acc(const float* __restrict__ soft_all,
                                             const float* __restrict__ qf,
                                             float* __restrict__ part) {
    __shared__ float soft_lds[16 * 64];
    __shared__ float qf_lds[16 * 128];
    int bid = blockIdx.x;
    int bq = bid >> 3;
    int rem = bid & 7;
    int sk0 = (rem & 1) * 64;
    int c0 = (rem >> 1) * 128;
    int q0 = bq * 256;
    int tid = threadIdx.x;
    int w = tid >> 6, lane = tid & 63;
    int wsk = (w & 1) * 32;
    int wc = (w >> 1) * 64;
    int lsk = (lane & 3) * 8;
    int lc = (lane >> 2) * 4;
    float acc[8][4];
#pragma unroll
    for (int i = 0; i < 8; i++)
#pragma unroll
        for (int j = 0; j < 4; j++) acc[i][j] = 0.f;

    for (int qb = 0; qb < 16; qb++) {
        int qbase = q0 + qb * 16;
#pragma unroll
        for (int i = 0; i < 4; i++) {
            int idx = i * 256 + tid;
            int j = idx >> 6, t = idx & 63;
            int skg = sk0 + t;
            float v = 0.f;
            if (skg < 96)
                v = soft_all[(size_t)(skg >> 5) * NQg * 32 + (size_t)(qbase + j) * 32 + (skg & 31)];
            soft_lds[j * 64 + t] = v;
        }
#pragma unroll
        for (int i = 0; i < 8; i++) {
            int idx = i * 256 + tid;
            int j = idx >> 7, t = idx & 127;
            qf_lds[j * 128 + t] = qf[(size_t)(qbase + j) * 512 + c0 + t];
        }
        __syncthreads();
#pragma unroll
        for (int j = 0; j < 16; j++) {
            float4 qv = *(float4*)&qf_lds[j * 128 + wc + lc];
            float4 s0 = *(float4*)&soft_lds[j * 64 + wsk + lsk];
            float4 s1 = *(float4*)&soft_lds[j * 64 + wsk + lsk + 4];
            float sv[8] = {s0.x, s0.y, s0.z, s0.w, s1.x, s1.y, s1.z, s1.w};
#pragma unroll
            for (int i = 0; i < 8; i++) {
                acc[i][0] += sv[i] * qv.x;
                acc[i][1] += sv[i] * qv.y;
                acc[i][2] += sv[i] * qv.z;
                acc[i][3] += sv[i] * qv.w;
            }
        }
        __syncthreads();
    }
    int cpos = c0 + wc + lc;
#pragma unroll
    for (int i = 0; i < 8; i++) {
        int sk = sk0 + wsk + lsk + i;
        if (sk < 96) {
            float4 v = make_float4(acc[i][0], acc[i][1], acc[i][2], acc[i][3]);
            *(float4*)&part[((size_t)bq * 96 + sk) * 512 + cpos] = v;
        }
    }
}

// ---------------- reduce partials -> wmean[sk][c] ----------------
__global__ void k_reduce(const float* __restrict__ part, const float* __restrict__ wsum,
                         float* __restrict__ wmean) {
    int idx = blockIdx.x * 256 + threadIdx.x;
    float s = 0.f;
#pragma unroll 8
    for (int bq = 0; bq < 64; bq++) s += part[(size_t)bq * 49152 + idx];
    int sk = idx >> 9;
    wmean[idx] = s / fmaxf(wsum[sk], 1e-6f);
}

// ---------------- MLP layer 1 ----------------
__global__ void k_mlp1(const float* __restrict__ refined, const float* __restrict__ wmean,
                       const float* __restrict__ W1, const float* __restrict__ b1,
                       float* __restrict__ hbuf, int s) {
    __shared__ float crow[256];
    int r = blockIdx.x >> 2, ks = blockIdx.x & 3;
    int t = threadIdx.x;
    int i0 = ks * 256;
    int gi = i0 + t;
    crow[t] = (gi < 512) ? refined[r * 512 + gi] : wmean[(s * 32 + r) * 512 + (gi - 512)];
    __syncthreads();
    int c = t, c2 = t + 256;
    float a0 = (ks == 0) ? b1[c] : 0.f;
    float a1 = (ks == 0) ? b1[c2] : 0.f;
    for (int ii = 0; ii < 256; ii++) {
        float cv = crow[ii];
        const float* wrow = W1 + (size_t)(i0 + ii) * 512;
        a0 += cv * wrow[c];
        a1 += cv * wrow[c2];
    }
    atomicAdd(&hbuf[r * 512 + c], a0);
    atomicAdd(&hbuf[r * 512 + c2], a1);
}

// ---------------- MLP layer 2 ----------------
__global__ void k_mlp2(const float* __restrict__ hbuf, const float* __restrict__ W2,
                       const float* __restrict__ b2, float* __restrict__ refined) {
    __shared__ float hrow[256];
    int r = blockIdx.x >> 1, ks = blockIdx.x & 1;
    int t = threadIdx.x;
    int i0 = ks * 256;
    hrow[t] = fmaxf(hbuf[r * 512 + i0 + t], 0.f);
    __syncthreads();
    int c = t, c2 = t + 256;
    float a0 = (ks == 0) ? b2[c] : 0.f;
    float a1 = (ks == 0) ? b2[c2] : 0.f;
    for (int ii = 0; ii < 256; ii++) {
        float hv = hrow[ii];
        const float* wrow = W2 + (size_t)(i0 + ii) * 512;
        a0 += hv * wrow[c];
        a1 += hv * wrow[c2];
    }
    atomicAdd(&refined[r * 512 + c], 0.1f * a0);
    atomicAdd(&refined[r * 512 + c2], 0.1f * a1);
}

// ---------------- copy refined -> d_out ----------------
__global__ void k_out(const float* __restrict__ refined, float* __restrict__ dout) {
    int idx = blockIdx.x * 256 + threadIdx.x;
    dout[idx] = refined[idx];
}

// ---------------- hpb[k][h] = prototypes @ Wp + bc1 ----------------
__global__ void k_hpb(const float* __restrict__ proto, const float* __restrict__ Wc1,
                      const float* __restrict__ bc1, float* __restrict__ hpb) {
    int r = blockIdx.x;
    int c = threadIdx.x;
    float a = bc1[c];
    for (int i = 0; i < 512; i++) a += proto[r * 512 + i] * Wc1[(size_t)i * 256 + c];
    hpb[r * 256 + c] = a;
}

// ---------------- pack Wq (=Wc1[512:]) to bf16 MFMA-B layout [k/8][n][8] ----------------
__global__ void k_wqpack(const float* __restrict__ Wc1, short* __restrict__ wqp) {
    int idx = blockIdx.x * 256 + threadIdx.x;   // 131072 = 512*256
    int k = idx >> 8, n = idx & 255;
    float v = Wc1[(size_t)(512 + k) * 256 + n];
    wqp[((k >> 3) * 256 + n) * 8 + (k & 7)] = f2bf(v);
}

// ---------------- MFMA bf16 GEMM: hq[16384][256] = qf @ Wq  (bf16 out) ----------------
// block = 64 M-rows x 256 N (all), 4 waves; wave w -> rows w*16..w*16+15, 16 N-tiles.
__global__ __launch_bounds__(256) void k_hq(const float* __restrict__ qf,
                                            const short* __restrict__ wqp,
                                            short* __restrict__ hq_g) {
    __shared__ short A_lds[64 * 56];     // row stride 56 bf16 = 112 B (16B-aligned, 2-way max)
    __shared__ short B_lds[8192];        // 16 KB packed chunk [q8][n][8]
    int tid = threadIdx.x;
    int w = tid >> 6, lane = tid & 63;
    int ml = lane & 15, q8 = lane >> 4;
    int m0 = blockIdx.x * 64;
    int arow = tid >> 2, akoff = (tid & 3) * 8;

    floatx4 acc[16];
#pragma unroll
    for (int t = 0; t < 16; t++) acc[t] = (floatx4){0.f, 0.f, 0.f, 0.f};

    for (int kc = 0; kc < 512; kc += 32) {
        // stage A: 64x32 fp32 -> bf16
        const float* arow_p = qf + (size_t)(m0 + arow) * 512 + kc + akoff;
        float4 a0 = *(const float4*)arow_p;
        float4 a1 = *(const float4*)(arow_p + 4);
        short8 av;
        av[0] = f2bf(a0.x); av[1] = f2bf(a0.y); av[2] = f2bf(a0.z); av[3] = f2bf(a0.w);
        av[4] = f2bf(a1.x); av[5] = f2bf(a1.y); av[6] = f2bf(a1.z); av[7] = f2bf(a1.w);
        *(short8*)&A_lds[arow * 56 + akoff] = av;
        // stage B: flat 16 KB copy of packed chunk
        int cbase = (kc >> 3) * 2048;
#pragma unroll
        for (int i = 0; i < 4; i++) {
            short8 bv = *(const short8*)&wqp[cbase + (i * 256 + tid) * 8];
            *(short8*)&B_lds[(i * 256 + tid) * 8] = bv;
        }
        __syncthreads();
        S8B8 af; af.s = *(short8*)&A_lds[(w * 16 + ml) * 56 + q8 * 8];
#pragma unroll
        for (int t = 0; t < 16; t++) {
            S8B8 bf; bf.s = *(short8*)&B_lds[(q8 * 256 + t * 16 + ml) * 8];
            acc[t] = __builtin_amdgcn_mfma_f32_16x16x32_bf16(af.b, bf.b, acc[t], 0, 0, 0);
        }
        __syncthreads();
    }
    // epilogue: C row = q8*4+r (within wave's 16 rows), col = t*16+ml
#pragma unroll
    for (int t = 0; t < 16; t++) {
        int col = t * 16 + ml;
#pragma unroll
        for (int r = 0; r < 4; r++) {
            int row = m0 + w * 16 + q8 * 4 + r;
            hq_g[(size_t)row * 256 + col] = f2bf(acc[t][r]);
        }
    }
}

// ---------------- confidence phase 2: per (q,k) relu-dot + sigmoid, mean over q ----------------
// grid 1024 blocks x 16 q; thread = (q = tid&15, kg = tid>>4), k0=kg, k1=kg+16
__global__ __launch_bounds__(256) void k_conf2(const short* __restrict__ hq_g,
                                               const float* __restrict__ hpb,
                                               const float* __restrict__ Wc2,
                                               const float* __restrict__ bc2p,
                                               float* __restrict__ dout) {
    __shared__ float hp_lds[32 * 260];   // stride 260 f32: conflict-free
    __shared__ short hq_lds[16 * 280];   // stride 280 bf16 = 560 B: 2-way max
    __shared__ float wc2s[256];
    __shared__ float confl[32];
    int tid = threadIdx.x;
    int q0 = blockIdx.x * 16;

    wc2s[tid] = Wc2[tid];
    if (tid < 32) confl[tid] = 0.f;
#pragma unroll
    for (int i = 0; i < 8; i++) {
        int idx = i * 1024 + tid * 4;
        int r = idx >> 8, c = idx & 255;
        *(float4*)&hp_lds[r * 260 + c] = *(const float4*)&hpb[idx];
    }
    {
        const short* hqs = hq_g + (size_t)q0 * 256;
        int r = tid >> 4, c = (tid & 15) * 16;
        *(short8*)&hq_lds[r * 280 + c] = *(const short8*)&hqs[r * 256 + c];
        *(short8*)&hq_lds[r * 280 + c + 8] = *(const short8*)&hqs[r * 256 + c + 8];
    }
    __syncthreads();

    int q = tid & 15, kg = tid >> 4;
    int k0 = kg, k1 = kg + 16;
    float s0 = 0.f, s1 = 0.f;
    for (int h = 0; h < 256; h += 4) {
        uint2 hv = *(uint2*)&hq_lds[q * 280 + h];
        float f0 = __uint_as_float((hv.x & 0xffffu) << 16);
        float f1 = __uint_as_float(hv.x & 0xffff0000u);
        float f2 = __uint_as_float((hv.y & 0xffffu) << 16);
        float f3 = __uint_as_float(hv.y & 0xffff0000u);
        float4 p0 = *(float4*)&hp_lds[k0 * 260 + h];
        float4 p1 = *(float4*)&hp_lds[k1 * 260 + h];
        float4 wv = *(float4*)&wc2s[h];
        s0 += fmaxf(p0.x + f0, 0.f) * wv.x;
        s0 += fmaxf(p0.y + f1, 0.f) * wv.y;
        s0 += fmaxf(p0.z + f2, 0.f) * wv.z;
        s0 += fmaxf(p0.w + f3, 0.f) * wv.w;
        s1 += fmaxf(p1.x + f0, 0.f) * wv.x;
        s1 += fmaxf(p1.y + f1, 0.f) * wv.y;
        s1 += fmaxf(p1.z + f2, 0.f) * wv.z;
        s1 += fmaxf(p1.w + f3, 0.f) * wv.w;
    }
    float bc2 = bc2p[0];
    float v0 = 1.f / (1.f + __expf(-(s0 + bc2)));
    float v1 = 1.f / (1.f + __expf(-(s1 + bc2)));
    atomicAdd(&confl[k0], v0);
    atomicAdd(&confl[k1], v1);
    __syncthreads();
    if (tid < 32) atomicAdd(&dout[16384 + tid], confl[tid] * (1.0f / 16384.0f));
}

extern "C" void kernel_launch(void* const* d_in, const int* in_sizes, int n_in,
                              void* d_out, int out_size, void* d_ws, size_t ws_size,
                              hipStream_t stream) {
    const float* proto = (const float*)d_in[0];
    const float* qf    = (const float*)d_in[1];
    const float* qd    = (const float*)d_in[2];
    const float* W1    = (const float*)d_in[3];
    const float* b1    = (const float*)d_in[4];
    const float* W2    = (const float*)d_in[5];
    const float* b2    = (const float*)d_in[6];
    const float* Wc1   = (const float*)d_in[7];
    const float* bc1   = (const float*)d_in[8];
    const float* Wc2   = (const float*)d_in[9];
    const float* bc2   = (const float*)d_in[10];
    float* out = (float*)d_out;

    float* ws = (float*)d_ws;
    float* soft_all = ws;                    // 3*16384*32 = 1,572,864 f
    float* part     = ws + 1572864;          // 64*96*512  = 3,145,728 f
    float* wsum     = ws + 4718592;          // 96
    float* wmean    = ws + 4718688;          // 49,152
    float* refined  = ws + 4767840;          // 16,384
    float* hbuf     = ws + 4784224;          // 16,384
    float* hpb      = ws + 4800608;          // 8,192
    short* wqp      = (short*)(ws + 4808800); // 131,072 bf16 (65,536 f)
    short* hq       = (short*)(ws + 4874336); // 16384*256 bf16 (2,097,152 f)

    hipMemsetAsync((char*)d_out + 16384 * sizeof(float), 0, 32 * sizeof(float), stream);
    k_init<<<64, 256, 0, stream>>>(proto, refined, wsum);
    k_soft<<<64, 256, 0, stream>>>(qd, soft_all);
    k_wsum<<<48, 256, 0, stream>>>(soft_all, wsum);
    k_acc<<<512, 256, 0, stream>>>(soft_all, qf, part);
    k_reduce<<<192, 256, 0, stream>>>(part, wsum, wmean);
    for (int s = 0; s < 3; s++) {
        hipMemsetAsync(hbuf, 0, 16384 * sizeof(float), stream);
        k_mlp1<<<128, 256, 0, stream>>>(refined, wmean, W1, b1, hbuf, s);
        k_mlp2<<<64, 256, 0, stream>>>(hbuf, W2, b2, refined);
    }
    k_out<<<64, 256, 0, stream>>>(refined, out);
    k_wqpack<<<512, 256, 0, stream>>>(Wc1, wqp);
    k_hq<<<256, 256, 0, stream>>>(qf, wqp, hq);
    k_hpb<<<32, 256, 0, stream>>>(proto, Wc1, bc1, hpb);
    k_conf2<<<1024, 256, 0, stream>>>(hq, hpb, Wc2, bc2, out);
}

// Round 3
// 238.476 us; speedup vs baseline: 1.4156x; 1.2644x over previous
//
#include <hip/hip_runtime.h>

#define KP 32
#define NQg 16384
#define CD 512
#define HC 256
#define NS 3

typedef __attribute__((ext_vector_type(8))) short short8;
typedef __attribute__((ext_vector_type(8))) __bf16 bf16x8;
typedef __attribute__((ext_vector_type(4))) float floatx4;

union S8B8 { short8 s; bf16x8 b; };

__device__ __forceinline__ short f2bf(float f) {
    union { float f; unsigned u; } v; v.f = f;
    unsigned r = v.u + 0x7fffu + ((v.u >> 16) & 1u);   // RNE
    return (short)(r >> 16);
}
__device__ __forceinline__ float bf2f(short s) {
    union { unsigned u; float f; } v; v.u = ((unsigned)(unsigned short)s) << 16;
    return v.f;
}

// ---------------- softmax over K=32 per query, 3 temps -> softT[96][16384] bf16 ----------------
__global__ __launch_bounds__(256) void k_soft(const float* __restrict__ qd,
                                              short* __restrict__ softT) {
    int q = blockIdx.x * 256 + threadIdx.x;
    float d[32];
    const float4* p = (const float4*)(qd + (size_t)q * 32);
#pragma unroll
    for (int j = 0; j < 8; j++) {
        float4 v = p[j];
        d[4 * j] = v.x; d[4 * j + 1] = v.y; d[4 * j + 2] = v.z; d[4 * j + 3] = v.w;
    }
#pragma unroll
    for (int s = 0; s < 3; s++) {
        float inv = -1.0f / (float)(s + 1);
        float e[32];
        float sum = 0.f;
#pragma unroll
        for (int k = 0; k < 32; k++) { e[k] = __expf(d[k] * inv); sum += e[k]; }
        float r = 1.0f / sum;
#pragma unroll
        for (int k = 0; k < 32; k++)
            softT[(size_t)(s * 32 + k) * NQg + q] = f2bf(e[k] * r);
    }
}

// ---------------- pack weights to bf16 MFMA-B layout + refined = proto ----------------
// W1p: [k/8][512][8] from W1[1024][512]; W2p: [k/8][512][8] from W2[512][512];
// wqp: [k/8][256][8] from Wc1[512:1024][256]; refined copy.
__global__ void k_pack(const float* __restrict__ W1, const float* __restrict__ W2,
                       const float* __restrict__ Wc1, const float* __restrict__ proto,
                       short* __restrict__ W1p, short* __restrict__ W2p,
                       short* __restrict__ wqp, float* __restrict__ refined) {
    int idx = blockIdx.x * 256 + threadIdx.x;   // < 933888
    if (idx < 524288) {
        int k = idx >> 9, n = idx & 511;
        W1p[((size_t)(k >> 3) * 512 + n) * 8 + (k & 7)] = f2bf(W1[idx]);
    } else if (idx < 786432) {
        int j = idx - 524288;
        int k = j >> 9, n = j & 511;
        W2p[((size_t)(k >> 3) * 512 + n) * 8 + (k & 7)] = f2bf(W2[j]);
    } else if (idx < 917504) {
        int j = idx - 786432;
        int k = j >> 8, n = j & 255;
        wqp[((size_t)(k >> 3) * 256 + n) * 8 + (k & 7)] = f2bf(Wc1[(size_t)(512 + k) * 256 + n]);
    } else {
        int j = idx - 917504;
        refined[j] = proto[j];
    }
}

// ---------------- wsum[sk] = sum_q softT[sk][q] ----------------
__global__ void k_wsum(const short* __restrict__ softT, float* __restrict__ wsum) {
    __shared__ float red[256];
    int sk = blockIdx.x;
    const short* row = softT + (size_t)sk * NQg;
    float s = 0.f;
#pragma unroll
    for (int j = 0; j < 8; j++) {
        short8 v = *(const short8*)&row[j * 2048 + threadIdx.x * 8];
#pragma unroll
        for (int i = 0; i < 8; i++) s += bf2f(v[i]);
    }
    red[threadIdx.x] = s;
    __syncthreads();
    for (int off = 128; off > 0; off >>= 1) {
        if (threadIdx.x < off) red[threadIdx.x] += red[threadIdx.x + off];
        __syncthreads();
    }
    if (threadIdx.x == 0) wsum[sk] = red[0];
}

// ---------------- MFMA: part[kc][96][512] = softT-chunk @ qf-chunk ----------------
// grid 256 = 64 K-chunks(256 q) x 4 N-slices(128 c). Wave: 6 m-tiles x 2 n-tiles.
__global__ __launch_bounds__(256) void k_wmean(const float* __restrict__ qf,
                                               const short* __restrict__ softT,
                                               float* __restrict__ part) {
    __shared__ short B_lds[128 * 40];    // [c][q] transposed, stride 40 shorts (80B, 16B-aligned)
    int tid = threadIdx.x;
    int lane = tid & 63, w = tid >> 6;
    int ml = lane & 15, q8 = lane >> 4;
    int kc = blockIdx.x >> 2, ns = blockIdx.x & 3;
    int c0 = ns * 128;
    int qbase0 = kc * 256;
    int c_l = 2 * lane;     // staging: 2 c-rows per thread
    int q_l = 8 * w;        // staging: 8 q per thread (per wave)

    floatx4 acc[6][2];
#pragma unroll
    for (int mt = 0; mt < 6; mt++)
#pragma unroll
        for (int nt = 0; nt < 2; nt++) acc[mt][nt] = (floatx4){0.f, 0.f, 0.f, 0.f};

    for (int step = 0; step < 8; step++) {
        int qb = qbase0 + step * 32;
        short8 sA, sB;
#pragma unroll
        for (int i = 0; i < 8; i++) {
            float2 v = *(const float2*)&qf[(size_t)(qb + q_l + i) * 512 + c0 + c_l];
            sA[i] = f2bf(v.x); sB[i] = f2bf(v.y);
        }
        __syncthreads();   // prev iteration's B reads complete
        *(short8*)&B_lds[c_l * 40 + q_l] = sA;
        *(short8*)&B_lds[(c_l + 1) * 40 + q_l] = sB;
        S8B8 a[6];
#pragma unroll
        for (int mt = 0; mt < 6; mt++)
            a[mt].s = *(const short8*)&softT[(size_t)(mt * 16 + ml) * NQg + qb + q8 * 8];
        __syncthreads();
#pragma unroll
        for (int nt = 0; nt < 2; nt++) {
            S8B8 b; b.s = *(short8*)&B_lds[(w * 32 + nt * 16 + ml) * 40 + q8 * 8];
#pragma unroll
            for (int mt = 0; mt < 6; mt++)
                acc[mt][nt] = __builtin_amdgcn_mfma_f32_16x16x32_bf16(a[mt].b, b.b, acc[mt][nt], 0, 0, 0);
        }
    }
    float* pbase = part + (size_t)kc * 96 * 512;
#pragma unroll
    for (int mt = 0; mt < 6; mt++) {
#pragma unroll
        for (int nt = 0; nt < 2; nt++) {
            int c = c0 + w * 32 + nt * 16 + ml;
#pragma unroll
            for (int r = 0; r < 4; r++) {
                int m = mt * 16 + q8 * 4 + r;
                pbase[(size_t)m * 512 + c] = acc[mt][nt][r];
            }
        }
    }
}

// ---------------- reduce partials -> wmean[sk][c] ----------------
__global__ void k_reduce(const float* __restrict__ part, const float* __restrict__ wsum,
                         float* __restrict__ wmean) {
    int idx = blockIdx.x * 256 + threadIdx.x;  // < 96*512
    float s = 0.f;
#pragma unroll 8
    for (int bq = 0; bq < 64; bq++) s += part[(size_t)bq * 49152 + idx];
    int sk = idx >> 9;
    wmean[idx] = s / fmaxf(wsum[sk], 1e-6f);
}

// ---------------- MLP layer 1 (MFMA): hb[32][512] = relu(concat @ W1 + b1) bf16 ----------------
// grid 8 n-blocks (64 n each); waves split K=1024 into quarters; LDS reduce.
__global__ __launch_bounds__(256) void k_mlp1(const float* __restrict__ refined,
                                              const float* __restrict__ wmean,
                                              const short* __restrict__ W1p,
                                              const float* __restrict__ b1,
                                              short* __restrict__ hb, int s) {
    __shared__ float red[4][32][68];
    int tid = threadIdx.x, lane = tid & 63, w = tid >> 6;
    int ml = lane & 15, q8 = lane >> 4;
    int nb = blockIdx.x;
    const float* srcA = (w < 2) ? refined : (wmean + (size_t)s * 32 * 512 - 512);
    int kw = w * 256;
    floatx4 acc[2][4];
#pragma unroll
    for (int mt = 0; mt < 2; mt++)
#pragma unroll
        for (int nt = 0; nt < 4; nt++) acc[mt][nt] = (floatx4){0.f, 0.f, 0.f, 0.f};

    for (int st = 0; st < 8; st++) {
        int k0 = kw + st * 32 + q8 * 8;
        S8B8 a[2];
#pragma unroll
        for (int mt = 0; mt < 2; mt++) {
            const float* p = &srcA[(size_t)(mt * 16 + ml) * 512 + k0];
            float4 f0 = *(const float4*)p;
            float4 f1 = *(const float4*)(p + 4);
            short8 t;
            t[0] = f2bf(f0.x); t[1] = f2bf(f0.y); t[2] = f2bf(f0.z); t[3] = f2bf(f0.w);
            t[4] = f2bf(f1.x); t[5] = f2bf(f1.y); t[6] = f2bf(f1.z); t[7] = f2bf(f1.w);
            a[mt].s = t;
        }
#pragma unroll
        for (int nt = 0; nt < 4; nt++) {
            int n = nb * 64 + nt * 16 + ml;
            S8B8 b; b.s = *(const short8*)&W1p[((size_t)(k0 >> 3) * 512 + n) * 8];
#pragma unroll
            for (int mt = 0; mt < 2; mt++)
                acc[mt][nt] = __builtin_amdgcn_mfma_f32_16x16x32_bf16(a[mt].b, b.b, acc[mt][nt], 0, 0, 0);
        }
    }
#pragma unroll
    for (int mt = 0; mt < 2; mt++)
#pragma unroll
        for (int nt = 0; nt < 4; nt++)
#pragma unroll
            for (int r = 0; r < 4; r++)
                red[w][mt * 16 + q8 * 4 + r][nt * 16 + ml] = acc[mt][nt][r];
    __syncthreads();
    int m = tid >> 3, n0 = (tid & 7) * 8;
    short8 o;
#pragma unroll
    for (int i = 0; i < 8; i++) {
        float v = b1[nb * 64 + n0 + i];
#pragma unroll
        for (int w4 = 0; w4 < 4; w4++) v += red[w4][m][n0 + i];
        o[i] = f2bf(fmaxf(v, 0.f));
    }
    *(short8*)&hb[(size_t)m * 512 + nb * 64 + n0] = o;
}

// ---------------- MLP layer 2 (MFMA): refined += 0.1*(hb @ W2 + b2); optional dout ----------------
__global__ __launch_bounds__(256) void k_mlp2(const short* __restrict__ hb,
                                              const short* __restrict__ W2p,
                                              const float* __restrict__ b2,
                                              float* __restrict__ refined,
                                              float* __restrict__ dout) {
    __shared__ float red[4][32][68];
    int tid = threadIdx.x, lane = tid & 63, w = tid >> 6;
    int ml = lane & 15, q8 = lane >> 4;
    int nb = blockIdx.x;
    int kw = w * 128;
    floatx4 acc[2][4];
#pragma unroll
    for (int mt = 0; mt < 2; mt++)
#pragma unroll
        for (int nt = 0; nt < 4; nt++) acc[mt][nt] = (floatx4){0.f, 0.f, 0.f, 0.f};

    for (int st = 0; st < 4; st++) {
        int k0 = kw + st * 32 + q8 * 8;
        S8B8 a[2];
#pragma unroll
        for (int mt = 0; mt < 2; mt++)
            a[mt].s = *(const short8*)&hb[(size_t)(mt * 16 + ml) * 512 + k0];
#pragma unroll
        for (int nt = 0; nt < 4; nt++) {
            int n = nb * 64 + nt * 16 + ml;
            S8B8 b; b.s = *(const short8*)&W2p[((size_t)(k0 >> 3) * 512 + n) * 8];
#pragma unroll
            for (int mt = 0; mt < 2; mt++)
                acc[mt][nt] = __builtin_amdgcn_mfma_f32_16x16x32_bf16(a[mt].b, b.b, acc[mt][nt], 0, 0, 0);
        }
    }
#pragma unroll
    for (int mt = 0; mt < 2; mt++)
#pragma unroll
        for (int nt = 0; nt < 4; nt++)
#pragma unroll
            for (int r = 0; r < 4; r++)
                red[w][mt * 16 + q8 * 4 + r][nt * 16 + ml] = acc[mt][nt][r];
    __syncthreads();
    int m = tid >> 3, n0 = (tid & 7) * 8;
#pragma unroll
    for (int i = 0; i < 8; i++) {
        int c = nb * 64 + n0 + i;
        float v = b2[c];
#pragma unroll
        for (int w4 = 0; w4 < 4; w4++) v += red[w4][m][n0 + i];
        float val = refined[(size_t)m * 512 + c] + 0.1f * v;
        refined[(size_t)m * 512 + c] = val;
        if (dout) dout[(size_t)m * 512 + c] = val;
    }
}

// ---------------- hpb[k][h] = prototypes @ Wp + bc1; also zero conf accumulators ----------------
__global__ void k_hpb(const float* __restrict__ proto, const float* __restrict__ Wc1,
                      const float* __restrict__ bc1, float* __restrict__ hpb,
                      float* __restrict__ dout) {
    int r = blockIdx.x;
    int c = threadIdx.x;
    if (c == 0) dout[16384 + r] = 0.f;
    float a = bc1[c];
    for (int i = 0; i < 512; i++) a += proto[r * 512 + i] * Wc1[(size_t)i * 256 + c];
    hpb[r * 256 + c] = a;
}

// ---------------- MFMA bf16 GEMM: hq[16384][256] = qf @ Wq (bf16 out) ----------------
__global__ __launch_bounds__(256) void k_hq(const float* __restrict__ qf,
                                            const short* __restrict__ wqp,
                                            short* __restrict__ hq_g) {
    __shared__ short A_lds[64 * 56];
    __shared__ short B_lds[8192];
    int tid = threadIdx.x;
    int w = tid >> 6, lane = tid & 63;
    int ml = lane & 15, q8 = lane >> 4;
    int m0 = blockIdx.x * 64;
    int arow = tid >> 2, akoff = (tid & 3) * 8;

    floatx4 acc[16];
#pragma unroll
    for (int t = 0; t < 16; t++) acc[t] = (floatx4){0.f, 0.f, 0.f, 0.f};

    for (int kc = 0; kc < 512; kc += 32) {
        const float* arow_p = qf + (size_t)(m0 + arow) * 512 + kc + akoff;
        float4 a0 = *(const float4*)arow_p;
        float4 a1 = *(const float4*)(arow_p + 4);
        short8 av;
        av[0] = f2bf(a0.x); av[1] = f2bf(a0.y); av[2] = f2bf(a0.z); av[3] = f2bf(a0.w);
        av[4] = f2bf(a1.x); av[5] = f2bf(a1.y); av[6] = f2bf(a1.z); av[7] = f2bf(a1.w);
        *(short8*)&A_lds[arow * 56 + akoff] = av;
        int cbase = (kc >> 3) * 2048;
#pragma unroll
        for (int i = 0; i < 4; i++) {
            short8 bv = *(const short8*)&wqp[cbase + (i * 256 + tid) * 8];
            *(short8*)&B_lds[(i * 256 + tid) * 8] = bv;
        }
        __syncthreads();
        S8B8 af; af.s = *(short8*)&A_lds[(w * 16 + ml) * 56 + q8 * 8];
#pragma unroll
        for (int t = 0; t < 16; t++) {
            S8B8 bf; bf.s = *(short8*)&B_lds[(q8 * 256 + t * 16 + ml) * 8];
            acc[t] = __builtin_amdgcn_mfma_f32_16x16x32_bf16(af.b, bf.b, acc[t], 0, 0, 0);
        }
        __syncthreads();
    }
#pragma unroll
    for (int t = 0; t < 16; t++) {
        int col = t * 16 + ml;
#pragma unroll
        for (int r = 0; r < 4; r++) {
            int row = m0 + w * 16 + q8 * 4 + r;
            hq_g[(size_t)row * 256 + col] = f2bf(acc[t][r]);
        }
    }
}

// ---------------- confidence phase 2 ----------------
__global__ __launch_bounds__(256) void k_conf2(const short* __restrict__ hq_g,
                                               const float* __restrict__ hpb,
                                               const float* __restrict__ Wc2,
                                               const float* __restrict__ bc2p,
                                               float* __restrict__ dout) {
    __shared__ float hp_lds[32 * 260];
    __shared__ short hq_lds[16 * 280];
    __shared__ float wc2s[256];
    __shared__ float confl[32];
    int tid = threadIdx.x;
    int q0 = blockIdx.x * 16;

    wc2s[tid] = Wc2[tid];
    if (tid < 32) confl[tid] = 0.f;
#pragma unroll
    for (int i = 0; i < 8; i++) {
        int idx = i * 1024 + tid * 4;
        int r = idx >> 8, c = idx & 255;
        *(float4*)&hp_lds[r * 260 + c] = *(const float4*)&hpb[idx];
    }
    {
        const short* hqs = hq_g + (size_t)q0 * 256;
        int r = tid >> 4, c = (tid & 15) * 16;
        *(short8*)&hq_lds[r * 280 + c] = *(const short8*)&hqs[r * 256 + c];
        *(short8*)&hq_lds[r * 280 + c + 8] = *(const short8*)&hqs[r * 256 + c + 8];
    }
    __syncthreads();

    int q = tid & 15, kg = tid >> 4;
    int k0 = kg, k1 = kg + 16;
    float s0 = 0.f, s1 = 0.f;
    for (int h = 0; h < 256; h += 4) {
        uint2 hv = *(uint2*)&hq_lds[q * 280 + h];
        float f0 = __uint_as_float((hv.x & 0xffffu) << 16);
        float f1 = __uint_as_float(hv.x & 0xffff0000u);
        float f2 = __uint_as_float((hv.y & 0xffffu) << 16);
        float f3 = __uint_as_float(hv.y & 0xffff0000u);
        float4 p0 = *(float4*)&hp_lds[k0 * 260 + h];
        float4 p1 = *(float4*)&hp_lds[k1 * 260 + h];
        float4 wv = *(float4*)&wc2s[h];
        s0 += fmaxf(p0.x + f0, 0.f) * wv.x;
        s0 += fmaxf(p0.y + f1, 0.f) * wv.y;
        s0 += fmaxf(p0.z + f2, 0.f) * wv.z;
        s0 += fmaxf(p0.w + f3, 0.f) * wv.w;
        s1 += fmaxf(p1.x + f0, 0.f) * wv.x;
        s1 += fmaxf(p1.y + f1, 0.f) * wv.y;
        s1 += fmaxf(p1.z + f2, 0.f) * wv.z;
        s1 += fmaxf(p1.w + f3, 0.f) * wv.w;
    }
    float bc2 = bc2p[0];
    float v0 = 1.f / (1.f + __expf(-(s0 + bc2)));
    float v1 = 1.f / (1.f + __expf(-(s1 + bc2)));
    atomicAdd(&confl[k0], v0);
    atomicAdd(&confl[k1], v1);
    __syncthreads();
    if (tid < 32) atomicAdd(&dout[16384 + tid], confl[tid] * (1.0f / 16384.0f));
}

extern "C" void kernel_launch(void* const* d_in, const int* in_sizes, int n_in,
                              void* d_out, int out_size, void* d_ws, size_t ws_size,
                              hipStream_t stream) {
    const float* proto = (const float*)d_in[0];
    const float* qf    = (const float*)d_in[1];
    const float* qd    = (const float*)d_in[2];
    const float* W1    = (const float*)d_in[3];
    const float* b1    = (const float*)d_in[4];
    const float* W2    = (const float*)d_in[5];
    const float* b2    = (const float*)d_in[6];
    const float* Wc1   = (const float*)d_in[7];
    const float* bc1   = (const float*)d_in[8];
    const float* Wc2   = (const float*)d_in[9];
    const float* bc2   = (const float*)d_in[10];
    float* out = (float*)d_out;

    float* ws = (float*)d_ws;
    short* softT   = (short*)ws;               // 1,572,864 shorts = 786,432 f
    float* part    = ws + 786432;              // 64*96*512 = 3,145,728 f
    float* wsum    = ws + 3932160;             // 96 (pad to 3,932,256)
    float* wmean   = ws + 3932256;             // 49,152 f
    float* refined = ws + 3981408;             // 16,384 f
    short* hb      = (short*)(ws + 3997792);   // 16,384 shorts = 8,192 f
    short* W1p     = (short*)(ws + 4005984);   // 524,288 shorts = 262,144 f
    short* W2p     = (short*)(ws + 4268128);   // 262,144 shorts = 131,072 f
    short* wqp     = (short*)(ws + 4399200);   // 131,072 shorts = 65,536 f
    float* hpb     = ws + 4464736;             // 8,192 f  (total 17.9 MB)
    short* hq      = (short*)part;             // alias: part dead after k_reduce

    k_soft<<<64, 256, 0, stream>>>(qd, softT);
    k_pack<<<3648, 256, 0, stream>>>(W1, W2, Wc1, proto, W1p, W2p, wqp, refined);
    k_wsum<<<96, 256, 0, stream>>>(softT, wsum);
    k_wmean<<<256, 256, 0, stream>>>(qf, softT, part);
    k_reduce<<<192, 256, 0, stream>>>(part, wsum, wmean);
    for (int s = 0; s < 3; s++) {
        k_mlp1<<<8, 256, 0, stream>>>(refined, wmean, W1p, b1, hb, s);
        k_mlp2<<<8, 256, 0, stream>>>(hb, W2p, b2, refined, (s == 2) ? out : nullptr);
    }
    k_hq<<<256, 256, 0, stream>>>(qf, wqp, hq);
    k_hpb<<<32, 256, 0, stream>>>(proto, Wc1, bc1, hpb, out);
    k_conf2<<<1024, 256, 0, stream>>>(hq, hpb, Wc2, bc2, out);
}

// Round 4
// 219.306 us; speedup vs baseline: 1.5393x; 1.0874x over previous
//
#include <hip/hip_runtime.h>

#define KP 32
#define NQg 16384
#define CD 512
#define HC 256
#define NS 3

typedef __attribute__((ext_vector_type(8))) short short8;
typedef __attribute__((ext_vector_type(4))) short short4_t;
typedef __attribute__((ext_vector_type(8))) __bf16 bf16x8;
typedef __attribute__((ext_vector_type(4))) float floatx4;

union S8B8 { short8 s; bf16x8 b; };

__device__ __forceinline__ short f2bf(float f) {
    union { float f; unsigned u; } v; v.f = f;
    unsigned r = v.u + 0x7fffu + ((v.u >> 16) & 1u);   // RNE
    return (short)(r >> 16);
}
__device__ __forceinline__ float bf2f(short s) {
    union { unsigned u; float f; } v; v.u = ((unsigned)(unsigned short)s) << 16;
    return v.f;
}

// ================ k_A: softmax (blocks 0..63) + weight pack / init (blocks 64..3711) ================
// softT[96][16384] bf16; W1p/W2p/wqp packed [k/8][n][8]; refined=proto; zero conf slots + barrier.
__global__ __launch_bounds__(256) void k_A(const float* __restrict__ qd,
                                           const float* __restrict__ W1, const float* __restrict__ W2,
                                           const float* __restrict__ Wc1, const float* __restrict__ proto,
                                           short* __restrict__ softT,
                                           short* __restrict__ W1p, short* __restrict__ W2p,
                                           short* __restrict__ wqp, float* __restrict__ refined,
                                           int* __restrict__ bar, float* __restrict__ dout) {
    int tid = threadIdx.x;
    if (blockIdx.x < 64) {
        int q = blockIdx.x * 256 + tid;
        float d[32];
        const float4* p = (const float4*)(qd + (size_t)q * 32);
#pragma unroll
        for (int j = 0; j < 8; j++) {
            float4 v = p[j];
            d[4 * j] = v.x; d[4 * j + 1] = v.y; d[4 * j + 2] = v.z; d[4 * j + 3] = v.w;
        }
#pragma unroll
        for (int s = 0; s < 3; s++) {
            float inv = -1.0f / (float)(s + 1);
            float e[32];
            float sum = 0.f;
#pragma unroll
            for (int k = 0; k < 32; k++) { e[k] = __expf(d[k] * inv); sum += e[k]; }
            float r = 1.0f / sum;
#pragma unroll
            for (int k = 0; k < 32; k++)
                softT[(size_t)(s * 32 + k) * NQg + q] = f2bf(e[k] * r);
        }
        return;
    }
    if (blockIdx.x == 64) {
        if (tid < 32) dout[16384 + tid] = 0.f;
        else if (tid < 40) bar[tid - 32] = 0;
    }
    int idx = (blockIdx.x - 64) * 256 + tid;   // < 933888
    if (idx < 524288) {
        int k = idx >> 9, n = idx & 511;
        W1p[((size_t)(k >> 3) * 512 + n) * 8 + (k & 7)] = f2bf(W1[idx]);
    } else if (idx < 786432) {
        int j = idx - 524288;
        int k = j >> 9, n = j & 511;
        W2p[((size_t)(k >> 3) * 512 + n) * 8 + (k & 7)] = f2bf(W2[j]);
    } else if (idx < 917504) {
        int j = idx - 786432;
        int k = j >> 8, n = j & 255;
        wqp[((size_t)(k >> 3) * 256 + n) * 8 + (k & 7)] = f2bf(Wc1[(size_t)(512 + k) * 256 + n]);
    } else {
        int j = idx - 917504;
        refined[j] = proto[j];
    }
}

// ================ MFMA: part[kc][96][512] = softT-chunk @ qf-chunk ================
__global__ __launch_bounds__(256) void k_wmean(const float* __restrict__ qf,
                                               const short* __restrict__ softT,
                                               float* __restrict__ part) {
    __shared__ short B_lds[128 * 40];
    int tid = threadIdx.x;
    int lane = tid & 63, w = tid >> 6;
    int ml = lane & 15, q8 = lane >> 4;
    int kc = blockIdx.x >> 2, ns = blockIdx.x & 3;
    int c0 = ns * 128;
    int qbase0 = kc * 256;
    int c_l = 2 * lane;
    int q_l = 8 * w;

    floatx4 acc[6][2];
#pragma unroll
    for (int mt = 0; mt < 6; mt++)
#pragma unroll
        for (int nt = 0; nt < 2; nt++) acc[mt][nt] = (floatx4){0.f, 0.f, 0.f, 0.f};

    for (int step = 0; step < 8; step++) {
        int qb = qbase0 + step * 32;
        short8 sA, sB;
#pragma unroll
        for (int i = 0; i < 8; i++) {
            float2 v = *(const float2*)&qf[(size_t)(qb + q_l + i) * 512 + c0 + c_l];
            sA[i] = f2bf(v.x); sB[i] = f2bf(v.y);
        }
        __syncthreads();
        *(short8*)&B_lds[c_l * 40 + q_l] = sA;
        *(short8*)&B_lds[(c_l + 1) * 40 + q_l] = sB;
        S8B8 a[6];
#pragma unroll
        for (int mt = 0; mt < 6; mt++)
            a[mt].s = *(const short8*)&softT[(size_t)(mt * 16 + ml) * NQg + qb + q8 * 8];
        __syncthreads();
#pragma unroll
        for (int nt = 0; nt < 2; nt++) {
            S8B8 b; b.s = *(short8*)&B_lds[(w * 32 + nt * 16 + ml) * 40 + q8 * 8];
#pragma unroll
            for (int mt = 0; mt < 6; mt++)
                acc[mt][nt] = __builtin_amdgcn_mfma_f32_16x16x32_bf16(a[mt].b, b.b, acc[mt][nt], 0, 0, 0);
        }
    }
    float* pbase = part + (size_t)kc * 96 * 512;
#pragma unroll
    for (int mt = 0; mt < 6; mt++) {
#pragma unroll
        for (int nt = 0; nt < 2; nt++) {
            int c = c0 + w * 32 + nt * 16 + ml;
#pragma unroll
            for (int r = 0; r < 4; r++) {
                int m = mt * 16 + q8 * 4 + r;
                pbase[(size_t)m * 512 + c] = acc[mt][nt][r];
            }
        }
    }
}

// ================ k_C: [0,192) reduce part + inline wsum -> wmean; [192,224) hpb ================
__global__ __launch_bounds__(256) void k_C(const float* __restrict__ part,
                                           const short* __restrict__ softT,
                                           float* __restrict__ wmean,
                                           const float* __restrict__ proto,
                                           const float* __restrict__ Wc1,
                                           const float* __restrict__ bc1,
                                           float* __restrict__ hpb) {
    int tid = threadIdx.x;
    if (blockIdx.x < 192) {
        __shared__ float red[256];
        __shared__ float wsv;
        int idx = blockIdx.x * 256 + tid;
        int sk = idx >> 9;
        const short* row = softT + (size_t)sk * NQg;
        float s = 0.f;
#pragma unroll
        for (int j = 0; j < 8; j++) {
            short8 v = *(const short8*)&row[j * 2048 + tid * 8];
#pragma unroll
            for (int i = 0; i < 8; i++) s += bf2f(v[i]);
        }
        red[tid] = s;
        __syncthreads();
        for (int off = 128; off > 0; off >>= 1) {
            if (tid < off) red[tid] += red[tid + off];
            __syncthreads();
        }
        if (tid == 0) wsv = fmaxf(red[0], 1e-6f);
        __syncthreads();
        float acc = 0.f;
#pragma unroll 8
        for (int bq = 0; bq < 64; bq++) acc += part[(size_t)bq * 49152 + idx];
        wmean[idx] = acc / wsv;
    } else {
        int r = blockIdx.x - 192;
        float a = bc1[tid];
        for (int i = 0; i < 512; i++) a += proto[r * 512 + i] * Wc1[(size_t)i * 256 + tid];
        hpb[r * 256 + tid] = a;
    }
}

// ================ fused 3-step MLP, 16 blocks, global spin barrier ================
__device__ __forceinline__ void gbar(int* bar, int phase, int nblk) {
    __syncthreads();
    if (threadIdx.x == 0) {
        __threadfence();
        __hip_atomic_fetch_add(&bar[phase], 1, __ATOMIC_ACQ_REL, __HIP_MEMORY_SCOPE_AGENT);
        while (__hip_atomic_load(&bar[phase], __ATOMIC_ACQUIRE, __HIP_MEMORY_SCOPE_AGENT) < nblk)
            __builtin_amdgcn_s_sleep(1);
    }
    __syncthreads();
}

__global__ __launch_bounds__(256, 1) void k_mlp(const float* __restrict__ wmean,
                                                const short* __restrict__ W1p,
                                                const float* __restrict__ b1,
                                                const short* __restrict__ W2p,
                                                const float* __restrict__ b2,
                                                float* __restrict__ refined,
                                                short* __restrict__ hb,
                                                int* __restrict__ bar,
                                                float* __restrict__ dout) {
    __shared__ float red[4][32][36];
    int tid = threadIdx.x, lane = tid & 63, w = tid >> 6;
    int ml = lane & 15, q8 = lane >> 4;
    int nb = blockIdx.x;          // 16 blocks x 32 n
    int phase = 0;

    for (int s = 0; s < 3; s++) {
        // ---- layer 1: hb[32][512]-slice = relu(concat @ W1 + b1), bf16 ----
        {
            const float* srcA = (w < 2) ? refined : (wmean + (size_t)s * 32 * 512 - 512);
            int kw = w * 256;
            floatx4 acc[2][2];
#pragma unroll
            for (int mt = 0; mt < 2; mt++)
#pragma unroll
                for (int nt = 0; nt < 2; nt++) acc[mt][nt] = (floatx4){0.f, 0.f, 0.f, 0.f};
            for (int st = 0; st < 8; st++) {
                int k0 = kw + st * 32 + q8 * 8;
                S8B8 a[2];
#pragma unroll
                for (int mt = 0; mt < 2; mt++) {
                    const float* p = &srcA[(size_t)(mt * 16 + ml) * 512 + k0];
                    float4 f0 = *(const float4*)p;
                    float4 f1 = *(const float4*)(p + 4);
                    short8 t;
                    t[0] = f2bf(f0.x); t[1] = f2bf(f0.y); t[2] = f2bf(f0.z); t[3] = f2bf(f0.w);
                    t[4] = f2bf(f1.x); t[5] = f2bf(f1.y); t[6] = f2bf(f1.z); t[7] = f2bf(f1.w);
                    a[mt].s = t;
                }
#pragma unroll
                for (int nt = 0; nt < 2; nt++) {
                    int n = nb * 32 + nt * 16 + ml;
                    S8B8 b; b.s = *(const short8*)&W1p[((size_t)(k0 >> 3) * 512 + n) * 8];
#pragma unroll
                    for (int mt = 0; mt < 2; mt++)
                        acc[mt][nt] = __builtin_amdgcn_mfma_f32_16x16x32_bf16(a[mt].b, b.b, acc[mt][nt], 0, 0, 0);
                }
            }
            __syncthreads();   // red[] reuse across phases
#pragma unroll
            for (int mt = 0; mt < 2; mt++)
#pragma unroll
                for (int nt = 0; nt < 2; nt++)
#pragma unroll
                    for (int r = 0; r < 4; r++)
                        red[w][mt * 16 + q8 * 4 + r][nt * 16 + ml] = acc[mt][nt][r];
            __syncthreads();
            int m = tid >> 3, n0 = (tid & 7) * 4;
            short4_t o;
#pragma unroll
            for (int i = 0; i < 4; i++) {
                float v = b1[nb * 32 + n0 + i];
#pragma unroll
                for (int w4 = 0; w4 < 4; w4++) v += red[w4][m][n0 + i];
                o[i] = f2bf(fmaxf(v, 0.f));
            }
            *(short4_t*)&hb[(size_t)m * 512 + nb * 32 + n0] = o;
        }
        gbar(bar, phase++, 16);
        // ---- layer 2: refined[:, slice] += 0.1*(hb @ W2 + b2) ----
        {
            int kw = w * 128;
            floatx4 acc[2][2];
#pragma unroll
            for (int mt = 0; mt < 2; mt++)
#pragma unroll
                for (int nt = 0; nt < 2; nt++) acc[mt][nt] = (floatx4){0.f, 0.f, 0.f, 0.f};
            for (int st = 0; st < 4; st++) {
                int k0 = kw + st * 32 + q8 * 8;
                S8B8 a[2];
#pragma unroll
                for (int mt = 0; mt < 2; mt++)
                    a[mt].s = *(const short8*)&hb[(size_t)(mt * 16 + ml) * 512 + k0];
#pragma unroll
                for (int nt = 0; nt < 2; nt++) {
                    int n = nb * 32 + nt * 16 + ml;
                    S8B8 b; b.s = *(const short8*)&W2p[((size_t)(k0 >> 3) * 512 + n) * 8];
#pragma unroll
                    for (int mt = 0; mt < 2; mt++)
                        acc[mt][nt] = __builtin_amdgcn_mfma_f32_16x16x32_bf16(a[mt].b, b.b, acc[mt][nt], 0, 0, 0);
                }
            }
            __syncthreads();
#pragma unroll
            for (int mt = 0; mt < 2; mt++)
#pragma unroll
                for (int nt = 0; nt < 2; nt++)
#pragma unroll
                    for (int r = 0; r < 4; r++)
                        red[w][mt * 16 + q8 * 4 + r][nt * 16 + ml] = acc[mt][nt][r];
            __syncthreads();
            int m = tid >> 3, n0 = (tid & 7) * 4;
#pragma unroll
            for (int i = 0; i < 4; i++) {
                int c = nb * 32 + n0 + i;
                float v = b2[c];
#pragma unroll
                for (int w4 = 0; w4 < 4; w4++) v += red[w4][m][n0 + i];
                float val = refined[(size_t)m * 512 + c] + 0.1f * v;
                refined[(size_t)m * 512 + c] = val;
                if (s == 2) dout[(size_t)m * 512 + c] = val;
            }
        }
        if (s < 2) gbar(bar, phase++, 16);
    }
}

// ================ MFMA bf16 GEMM: hq[16384][256] = qf @ Wq (bf16 out) ================
__global__ __launch_bounds__(256) void k_hq(const float* __restrict__ qf,
                                            const short* __restrict__ wqp,
                                            short* __restrict__ hq_g) {
    __shared__ short A_lds[64 * 56];
    __shared__ short B_lds[8192];
    int tid = threadIdx.x;
    int w = tid >> 6, lane = tid & 63;
    int ml = lane & 15, q8 = lane >> 4;
    int m0 = blockIdx.x * 64;
    int arow = tid >> 2, akoff = (tid & 3) * 8;

    floatx4 acc[16];
#pragma unroll
    for (int t = 0; t < 16; t++) acc[t] = (floatx4){0.f, 0.f, 0.f, 0.f};

    for (int kc = 0; kc < 512; kc += 32) {
        const float* arow_p = qf + (size_t)(m0 + arow) * 512 + kc + akoff;
        float4 a0 = *(const float4*)arow_p;
        float4 a1 = *(const float4*)(arow_p + 4);
        short8 av;
        av[0] = f2bf(a0.x); av[1] = f2bf(a0.y); av[2] = f2bf(a0.z); av[3] = f2bf(a0.w);
        av[4] = f2bf(a1.x); av[5] = f2bf(a1.y); av[6] = f2bf(a1.z); av[7] = f2bf(a1.w);
        *(short8*)&A_lds[arow * 56 + akoff] = av;
        int cbase = (kc >> 3) * 2048;
#pragma unroll
        for (int i = 0; i < 4; i++) {
            short8 bv = *(const short8*)&wqp[cbase + (i * 256 + tid) * 8];
            *(short8*)&B_lds[(i * 256 + tid) * 8] = bv;
        }
        __syncthreads();
        S8B8 af; af.s = *(short8*)&A_lds[(w * 16 + ml) * 56 + q8 * 8];
#pragma unroll
        for (int t = 0; t < 16; t++) {
            S8B8 bf; bf.s = *(short8*)&B_lds[(q8 * 256 + t * 16 + ml) * 8];
            acc[t] = __builtin_amdgcn_mfma_f32_16x16x32_bf16(af.b, bf.b, acc[t], 0, 0, 0);
        }
        __syncthreads();
    }
#pragma unroll
    for (int t = 0; t < 16; t++) {
        int col = t * 16 + ml;
#pragma unroll
        for (int r = 0; r < 4; r++) {
            int row = m0 + w * 16 + q8 * 4 + r;
            hq_g[(size_t)row * 256 + col] = f2bf(acc[t][r]);
        }
    }
}

// ================ confidence phase 2 ================
__global__ __launch_bounds__(256) void k_conf2(const short* __restrict__ hq_g,
                                               const float* __restrict__ hpb,
                                               const float* __restrict__ Wc2,
                                               const float* __restrict__ bc2p,
                                               float* __restrict__ dout) {
    __shared__ float hp_lds[32 * 260];
    __shared__ short hq_lds[16 * 280];
    __shared__ float wc2s[256];
    __shared__ float confl[32];
    int tid = threadIdx.x;
    int q0 = blockIdx.x * 16;

    wc2s[tid] = Wc2[tid];
    if (tid < 32) confl[tid] = 0.f;
#pragma unroll
    for (int i = 0; i < 8; i++) {
        int idx = i * 1024 + tid * 4;
        int r = idx >> 8, c = idx & 255;
        *(float4*)&hp_lds[r * 260 + c] = *(const float4*)&hpb[idx];
    }
    {
        const short* hqs = hq_g + (size_t)q0 * 256;
        int r = tid >> 4, c = (tid & 15) * 16;
        *(short8*)&hq_lds[r * 280 + c] = *(const short8*)&hqs[r * 256 + c];
        *(short8*)&hq_lds[r * 280 + c + 8] = *(const short8*)&hqs[r * 256 + c + 8];
    }
    __syncthreads();

    int q = tid & 15, kg = tid >> 4;
    int k0 = kg, k1 = kg + 16;
    float s0 = 0.f, s1 = 0.f;
    for (int h = 0; h < 256; h += 4) {
        uint2 hv = *(uint2*)&hq_lds[q * 280 + h];
        float f0 = __uint_as_float((hv.x & 0xffffu) << 16);
        float f1 = __uint_as_float(hv.x & 0xffff0000u);
        float f2 = __uint_as_float((hv.y & 0xffffu) << 16);
        float f3 = __uint_as_float(hv.y & 0xffff0000u);
        float4 p0 = *(float4*)&hp_lds[k0 * 260 + h];
        float4 p1 = *(float4*)&hp_lds[k1 * 260 + h];
        float4 wv = *(float4*)&wc2s[h];
        s0 += fmaxf(p0.x + f0, 0.f) * wv.x;
        s0 += fmaxf(p0.y + f1, 0.f) * wv.y;
        s0 += fmaxf(p0.z + f2, 0.f) * wv.z;
        s0 += fmaxf(p0.w + f3, 0.f) * wv.w;
        s1 += fmaxf(p1.x + f0, 0.f) * wv.x;
        s1 += fmaxf(p1.y + f1, 0.f) * wv.y;
        s1 += fmaxf(p1.z + f2, 0.f) * wv.z;
        s1 += fmaxf(p1.w + f3, 0.f) * wv.w;
    }
    float bc2 = bc2p[0];
    float v0 = 1.f / (1.f + __expf(-(s0 + bc2)));
    float v1 = 1.f / (1.f + __expf(-(s1 + bc2)));
    atomicAdd(&confl[k0], v0);
    atomicAdd(&confl[k1], v1);
    __syncthreads();
    if (tid < 32) atomicAdd(&dout[16384 + tid], confl[tid] * (1.0f / 16384.0f));
}

extern "C" void kernel_launch(void* const* d_in, const int* in_sizes, int n_in,
                              void* d_out, int out_size, void* d_ws, size_t ws_size,
                              hipStream_t stream) {
    const float* proto = (const float*)d_in[0];
    const float* qf    = (const float*)d_in[1];
    const float* qd    = (const float*)d_in[2];
    const float* W1    = (const float*)d_in[3];
    const float* b1    = (const float*)d_in[4];
    const float* W2    = (const float*)d_in[5];
    const float* b2    = (const float*)d_in[6];
    const float* Wc1   = (const float*)d_in[7];
    const float* bc1   = (const float*)d_in[8];
    const float* Wc2   = (const float*)d_in[9];
    const float* bc2   = (const float*)d_in[10];
    float* out = (float*)d_out;

    float* ws = (float*)d_ws;
    short* softT   = (short*)ws;               // 1,572,864 shorts = 786,432 f
    float* part    = ws + 786432;              // 64*96*512 = 3,145,728 f
    float* wmean   = ws + 3932256;             // 49,152 f
    float* refined = ws + 3981408;             // 16,384 f
    short* hb      = (short*)(ws + 3997792);   // 16,384 shorts = 8,192 f
    short* W1p     = (short*)(ws + 4005984);   // 524,288 shorts
    short* W2p     = (short*)(ws + 4268128);   // 262,144 shorts
    short* wqp     = (short*)(ws + 4399200);   // 131,072 shorts
    float* hpb     = ws + 4464736;             // 8,192 f
    int*   bar     = (int*)(ws + 4472928);     // 8 ints
    short* hq      = (short*)part;             // alias: part dead after k_C

    k_A<<<3712, 256, 0, stream>>>(qd, W1, W2, Wc1, proto, softT, W1p, W2p, wqp, refined, bar, out);
    k_wmean<<<256, 256, 0, stream>>>(qf, softT, part);
    k_C<<<224, 256, 0, stream>>>(part, softT, wmean, proto, Wc1, bc1, hpb);
    k_mlp<<<16, 256, 0, stream>>>(wmean, W1p, b1, W2p, b2, refined, hb, bar, out);
    k_hq<<<256, 256, 0, stream>>>(qf, wqp, hq);
    k_conf2<<<1024, 256, 0, stream>>>(hq, hpb, Wc2, bc2, out);
}

// Round 5
// 188.799 us; speedup vs baseline: 1.7880x; 1.1616x over previous
//
#include <hip/hip_runtime.h>

#define KP 32
#define NQg 16384
#define CD 512
#define HC 256
#define NS 3

typedef __attribute__((ext_vector_type(8))) short short8;
typedef __attribute__((ext_vector_type(4))) short short4_t;
typedef __attribute__((ext_vector_type(8))) __bf16 bf16x8;
typedef __attribute__((ext_vector_type(4))) float floatx4;

union S8B8 { short8 s; bf16x8 b; };

__device__ __forceinline__ short f2bf(float f) {
    union { float f; unsigned u; } v; v.f = f;
    unsigned r = v.u + 0x7fffu + ((v.u >> 16) & 1u);   // RNE
    return (short)(r >> 16);
}
__device__ __forceinline__ float bf2f(short s) {
    union { unsigned u; float f; } v; v.u = ((unsigned)(unsigned short)s) << 16;
    return v.f;
}

// ================ k_A: softmax | packs | qf->bf16 | zeros ================
// blocks 0..63: softmax -> softT[96][16384] bf16
// blocks 64..3711: pack W1p/W2p/wqp + refined=proto (+block 64: zero conf/bar)
// blocks 3712..3903: zero wmean accumulator
// blocks 3904..12095: cast qf -> qf2b bf16
__global__ __launch_bounds__(256) void k_A(const float* __restrict__ qd,
                                           const float* __restrict__ W1, const float* __restrict__ W2,
                                           const float* __restrict__ Wc1, const float* __restrict__ proto,
                                           const float* __restrict__ qf,
                                           short* __restrict__ softT,
                                           short* __restrict__ W1p, short* __restrict__ W2p,
                                           short* __restrict__ wqp, float* __restrict__ refined,
                                           short* __restrict__ qf2b, float* __restrict__ wmean,
                                           int* __restrict__ bar, float* __restrict__ dout) {
    int tid = threadIdx.x;
    int bid = blockIdx.x;
    if (bid < 64) {
        int q = bid * 256 + tid;
        float d[32];
        const float4* p = (const float4*)(qd + (size_t)q * 32);
#pragma unroll
        for (int j = 0; j < 8; j++) {
            float4 v = p[j];
            d[4 * j] = v.x; d[4 * j + 1] = v.y; d[4 * j + 2] = v.z; d[4 * j + 3] = v.w;
        }
#pragma unroll
        for (int s = 0; s < 3; s++) {
            float inv = -1.0f / (float)(s + 1);
            float e[32];
            float sum = 0.f;
#pragma unroll
            for (int k = 0; k < 32; k++) { e[k] = __expf(d[k] * inv); sum += e[k]; }
            float r = 1.0f / sum;
#pragma unroll
            for (int k = 0; k < 32; k++)
                softT[(size_t)(s * 32 + k) * NQg + q] = f2bf(e[k] * r);
        }
        return;
    }
    if (bid < 3712) {
        if (bid == 64) {
            if (tid < 32) dout[16384 + tid] = 0.f;
            else if (tid < 40) bar[tid - 32] = 0;
        }
        int idx = (bid - 64) * 256 + tid;   // < 933888
        if (idx < 524288) {
            int k = idx >> 9, n = idx & 511;
            W1p[((size_t)(k >> 3) * 512 + n) * 8 + (k & 7)] = f2bf(W1[idx]);
        } else if (idx < 786432) {
            int j = idx - 524288;
            int k = j >> 9, n = j & 511;
            W2p[((size_t)(k >> 3) * 512 + n) * 8 + (k & 7)] = f2bf(W2[j]);
        } else if (idx < 917504) {
            int j = idx - 786432;
            int k = j >> 8, n = j & 255;
            wqp[((size_t)(k >> 3) * 256 + n) * 8 + (k & 7)] = f2bf(Wc1[(size_t)(512 + k) * 256 + n]);
        } else {
            int j = idx - 917504;
            refined[j] = proto[j];
        }
        return;
    }
    if (bid < 3904) {
        int idx = (bid - 3712) * 256 + tid;   // < 49152
        wmean[idx] = 0.f;
        return;
    }
    {
        int j = (bid - 3904) * 256 + tid;     // < 2,097,152 ; 4 elems each
        float4 v = *(const float4*)&qf[(size_t)j * 4];
        short4_t o;
        o[0] = f2bf(v.x); o[1] = f2bf(v.y); o[2] = f2bf(v.z); o[3] = f2bf(v.w);
        *(short4_t*)&qf2b[(size_t)j * 4] = o;
    }
}

// ================ k_B: blocks 0..255 wmean-MFMA (atomic accumulate) | 256..511 hq-MFMA ================
__global__ __launch_bounds__(256) void k_B(const short* __restrict__ qf2b,
                                           const short* __restrict__ softT,
                                           const short* __restrict__ wqp,
                                           float* __restrict__ wmean,
                                           short* __restrict__ hq_g) {
    __shared__ short B_lds[128 * 40];
    int tid = threadIdx.x;
    int lane = tid & 63, w = tid >> 6;
    int ml = lane & 15, q8 = lane >> 4;

    if (blockIdx.x < 256) {
        // ---- wmean partial: softT[96 x 256q-chunk] @ qf2b[256q x 128c-slice] ----
        int kc = blockIdx.x >> 2, ns = blockIdx.x & 3;
        int c0 = ns * 128;
        int qbase0 = kc * 256;
        int c_l = 2 * lane;
        int q_l = 8 * w;

        floatx4 acc[6][2];
#pragma unroll
        for (int mt = 0; mt < 6; mt++)
#pragma unroll
            for (int nt = 0; nt < 2; nt++) acc[mt][nt] = (floatx4){0.f, 0.f, 0.f, 0.f};

        for (int step = 0; step < 8; step++) {
            int qb = qbase0 + step * 32;
            short8 sA, sB;
#pragma unroll
            for (int i = 0; i < 8; i++) {
                unsigned u = *(const unsigned*)&qf2b[(size_t)(qb + q_l + i) * 512 + c0 + c_l];
                sA[i] = (short)(u & 0xffffu);
                sB[i] = (short)(u >> 16);
            }
            __syncthreads();
            *(short8*)&B_lds[c_l * 40 + q_l] = sA;
            *(short8*)&B_lds[(c_l + 1) * 40 + q_l] = sB;
            S8B8 a[6];
#pragma unroll
            for (int mt = 0; mt < 6; mt++)
                a[mt].s = *(const short8*)&softT[(size_t)(mt * 16 + ml) * NQg + qb + q8 * 8];
            __syncthreads();
#pragma unroll
            for (int nt = 0; nt < 2; nt++) {
                S8B8 b; b.s = *(short8*)&B_lds[(w * 32 + nt * 16 + ml) * 40 + q8 * 8];
#pragma unroll
                for (int mt = 0; mt < 6; mt++)
                    acc[mt][nt] = __builtin_amdgcn_mfma_f32_16x16x32_bf16(a[mt].b, b.b, acc[mt][nt], 0, 0, 0);
            }
        }
#pragma unroll
        for (int mt = 0; mt < 6; mt++) {
#pragma unroll
            for (int nt = 0; nt < 2; nt++) {
                int c = c0 + w * 32 + nt * 16 + ml;
#pragma unroll
                for (int r = 0; r < 4; r++) {
                    int m = mt * 16 + q8 * 4 + r;
                    atomicAdd(&wmean[(size_t)m * 512 + c], acc[mt][nt][r]);
                }
            }
        }
    } else {
        // ---- hq: qf2b[64 rows] @ wqp -> hq[16384][256]; LDS-free, barrier-free ----
        int m0 = (blockIdx.x - 256) * 64;
        int n0 = w * 64;
        floatx4 acc[4][4];
#pragma unroll
        for (int mt = 0; mt < 4; mt++)
#pragma unroll
            for (int nt = 0; nt < 4; nt++) acc[mt][nt] = (floatx4){0.f, 0.f, 0.f, 0.f};

#pragma unroll 4
        for (int kc = 0; kc < 512; kc += 32) {
            S8B8 a[4], b[4];
#pragma unroll
            for (int mt = 0; mt < 4; mt++)
                a[mt].s = *(const short8*)&qf2b[(size_t)(m0 + mt * 16 + ml) * 512 + kc + q8 * 8];
#pragma unroll
            for (int nt = 0; nt < 4; nt++)
                b[nt].s = *(const short8*)&wqp[((size_t)((kc >> 3) + q8) * 256 + n0 + nt * 16 + ml) * 8];
#pragma unroll
            for (int mt = 0; mt < 4; mt++)
#pragma unroll
                for (int nt = 0; nt < 4; nt++)
                    acc[mt][nt] = __builtin_amdgcn_mfma_f32_16x16x32_bf16(a[mt].b, b[nt].b, acc[mt][nt], 0, 0, 0);
        }
#pragma unroll
        for (int mt = 0; mt < 4; mt++)
#pragma unroll
            for (int nt = 0; nt < 4; nt++) {
                int col = n0 + nt * 16 + ml;
#pragma unroll
                for (int r = 0; r < 4; r++) {
                    int row = m0 + mt * 16 + q8 * 4 + r;
                    hq_g[(size_t)row * 256 + col] = f2bf(acc[mt][nt][r]);
                }
            }
    }
}

// ================ k_C: blocks 0..95 wsum+divide | 96..127 hpb ================
__global__ __launch_bounds__(256) void k_C(const short* __restrict__ softT,
                                           float* __restrict__ wmean,
                                           const float* __restrict__ proto,
                                           const float* __restrict__ Wc1,
                                           const float* __restrict__ bc1,
                                           float* __restrict__ hpb) {
    int tid = threadIdx.x;
    if (blockIdx.x < 96) {
        __shared__ float red[256];
        int sk = blockIdx.x;
        const short* row = softT + (size_t)sk * NQg;
        float s = 0.f;
#pragma unroll
        for (int j = 0; j < 8; j++) {
            short8 v = *(const short8*)&row[j * 2048 + tid * 8];
#pragma unroll
            for (int i = 0; i < 8; i++) s += bf2f(v[i]);
        }
        red[tid] = s;
        __syncthreads();
        for (int off = 128; off > 0; off >>= 1) {
            if (tid < off) red[tid] += red[tid + off];
            __syncthreads();
        }
        float inv = 1.0f / fmaxf(red[0], 1e-6f);
        wmean[(size_t)sk * 512 + tid] *= inv;
        wmean[(size_t)sk * 512 + tid + 256] *= inv;
    } else {
        int r = blockIdx.x - 96;
        float a = bc1[tid];
        for (int i = 0; i < 512; i++) a += proto[r * 512 + i] * Wc1[(size_t)i * 256 + tid];
        hpb[r * 256 + tid] = a;
    }
}

// ================ global spin barrier (16 co-resident blocks) ================
__device__ __forceinline__ void gbar(int* bar, int phase, int nblk) {
    __syncthreads();
    if (threadIdx.x == 0) {
        __threadfence();
        __hip_atomic_fetch_add(&bar[phase], 1, __ATOMIC_ACQ_REL, __HIP_MEMORY_SCOPE_AGENT);
        while (__hip_atomic_load(&bar[phase], __ATOMIC_ACQUIRE, __HIP_MEMORY_SCOPE_AGENT) < nblk)
            __builtin_amdgcn_s_sleep(1);
    }
    __syncthreads();
}

// ================ k_D: blocks 0..15 fused 3-step MLP | 16..1039 confidence ================
__global__ __launch_bounds__(256) void k_D(const float* __restrict__ wmean,
                                           const short* __restrict__ W1p,
                                           const float* __restrict__ b1,
                                           const short* __restrict__ W2p,
                                           const float* __restrict__ b2,
                                           float* __restrict__ refined,
                                           short* __restrict__ hb,
                                           int* __restrict__ bar,
                                           const short* __restrict__ hq_g,
                                           const float* __restrict__ hpb,
                                           const float* __restrict__ Wc2,
                                           const float* __restrict__ bc2p,
                                           float* __restrict__ dout) {
    __shared__ float smem[10880];   // 43.5 KB, aliased per path
    int tid = threadIdx.x, lane = tid & 63, w = tid >> 6;
    int ml = lane & 15, q8 = lane >> 4;

    if (blockIdx.x < 16) {
        float (*red)[32][36] = (float(*)[32][36])smem;
        int nb = blockIdx.x;
        int phase = 0;
        for (int s = 0; s < 3; s++) {
            {   // layer 1: hb-slice = relu(concat @ W1 + b1) bf16
                const float* srcA = (w < 2) ? refined : (wmean + (size_t)s * 32 * 512 - 512);
                int kw = w * 256;
                floatx4 acc[2][2];
#pragma unroll
                for (int mt = 0; mt < 2; mt++)
#pragma unroll
                    for (int nt = 0; nt < 2; nt++) acc[mt][nt] = (floatx4){0.f, 0.f, 0.f, 0.f};
                for (int st = 0; st < 8; st++) {
                    int k0 = kw + st * 32 + q8 * 8;
                    S8B8 a[2];
#pragma unroll
                    for (int mt = 0; mt < 2; mt++) {
                        const float* p = &srcA[(size_t)(mt * 16 + ml) * 512 + k0];
                        float4 f0 = *(const float4*)p;
                        float4 f1 = *(const float4*)(p + 4);
                        short8 t;
                        t[0] = f2bf(f0.x); t[1] = f2bf(f0.y); t[2] = f2bf(f0.z); t[3] = f2bf(f0.w);
                        t[4] = f2bf(f1.x); t[5] = f2bf(f1.y); t[6] = f2bf(f1.z); t[7] = f2bf(f1.w);
                        a[mt].s = t;
                    }
#pragma unroll
                    for (int nt = 0; nt < 2; nt++) {
                        int n = nb * 32 + nt * 16 + ml;
                        S8B8 b; b.s = *(const short8*)&W1p[((size_t)(k0 >> 3) * 512 + n) * 8];
#pragma unroll
                        for (int mt = 0; mt < 2; mt++)
                            acc[mt][nt] = __builtin_amdgcn_mfma_f32_16x16x32_bf16(a[mt].b, b.b, acc[mt][nt], 0, 0, 0);
                    }
                }
                __syncthreads();
#pragma unroll
                for (int mt = 0; mt < 2; mt++)
#pragma unroll
                    for (int nt = 0; nt < 2; nt++)
#pragma unroll
                        for (int r = 0; r < 4; r++)
                            red[w][mt * 16 + q8 * 4 + r][nt * 16 + ml] = acc[mt][nt][r];
                __syncthreads();
                int m = tid >> 3, n0 = (tid & 7) * 4;
                short4_t o;
#pragma unroll
                for (int i = 0; i < 4; i++) {
                    float v = b1[nb * 32 + n0 + i];
#pragma unroll
                    for (int w4 = 0; w4 < 4; w4++) v += red[w4][m][n0 + i];
                    o[i] = f2bf(fmaxf(v, 0.f));
                }
                *(short4_t*)&hb[(size_t)m * 512 + nb * 32 + n0] = o;
            }
            gbar(bar, phase++, 16);
            {   // layer 2: refined[:, slice] += 0.1*(hb @ W2 + b2)
                int kw = w * 128;
                floatx4 acc[2][2];
#pragma unroll
                for (int mt = 0; mt < 2; mt++)
#pragma unroll
                    for (int nt = 0; nt < 2; nt++) acc[mt][nt] = (floatx4){0.f, 0.f, 0.f, 0.f};
                for (int st = 0; st < 4; st++) {
                    int k0 = kw + st * 32 + q8 * 8;
                    S8B8 a[2];
#pragma unroll
                    for (int mt = 0; mt < 2; mt++)
                        a[mt].s = *(const short8*)&hb[(size_t)(mt * 16 + ml) * 512 + k0];
#pragma unroll
                    for (int nt = 0; nt < 2; nt++) {
                        int n = nb * 32 + nt * 16 + ml;
                        S8B8 b; b.s = *(const short8*)&W2p[((size_t)(k0 >> 3) * 512 + n) * 8];
#pragma unroll
                        for (int mt = 0; mt < 2; mt++)
                            acc[mt][nt] = __builtin_amdgcn_mfma_f32_16x16x32_bf16(a[mt].b, b.b, acc[mt][nt], 0, 0, 0);
                    }
                }
                __syncthreads();
#pragma unroll
                for (int mt = 0; mt < 2; mt++)
#pragma unroll
                    for (int nt = 0; nt < 2; nt++)
#pragma unroll
                        for (int r = 0; r < 4; r++)
                            red[w][mt * 16 + q8 * 4 + r][nt * 16 + ml] = acc[mt][nt][r];
                __syncthreads();
                int m = tid >> 3, n0 = (tid & 7) * 4;
#pragma unroll
                for (int i = 0; i < 4; i++) {
                    int c = nb * 32 + n0 + i;
                    float v = b2[c];
#pragma unroll
                    for (int w4 = 0; w4 < 4; w4++) v += red[w4][m][n0 + i];
                    float val = refined[(size_t)m * 512 + c] + 0.1f * v;
                    refined[(size_t)m * 512 + c] = val;
                    if (s == 2) dout[(size_t)m * 512 + c] = val;
                }
            }
            if (s < 2) gbar(bar, phase++, 16);
        }
    } else {
        float* hp_lds = smem;                        // 32*260 f
        short* hq_lds = (short*)(smem + 8320);       // 16*280 s
        float* wc2s   = smem + 8320 + 2240;          // 256 f
        float* confl  = smem + 8320 + 2240 + 256;    // 32 f
        int q0 = (blockIdx.x - 16) * 16;

        wc2s[tid] = Wc2[tid];
        if (tid < 32) confl[tid] = 0.f;
#pragma unroll
        for (int i = 0; i < 8; i++) {
            int idx = i * 1024 + tid * 4;
            int r = idx >> 8, c = idx & 255;
            *(float4*)&hp_lds[r * 260 + c] = *(const float4*)&hpb[idx];
        }
        {
            const short* hqs = hq_g + (size_t)q0 * 256;
            int r = tid >> 4, c = (tid & 15) * 16;
            *(short8*)&hq_lds[r * 280 + c] = *(const short8*)&hqs[r * 256 + c];
            *(short8*)&hq_lds[r * 280 + c + 8] = *(const short8*)&hqs[r * 256 + c + 8];
        }
        __syncthreads();

        int q = tid & 15, kg = tid >> 4;
        int k0 = kg, k1 = kg + 16;
        float s0 = 0.f, s1 = 0.f;
        for (int h = 0; h < 256; h += 4) {
            uint2 hv = *(uint2*)&hq_lds[q * 280 + h];
            float f0 = __uint_as_float((hv.x & 0xffffu) << 16);
            float f1 = __uint_as_float(hv.x & 0xffff0000u);
            float f2 = __uint_as_float((hv.y & 0xffffu) << 16);
            float f3 = __uint_as_float(hv.y & 0xffff0000u);
            float4 p0 = *(float4*)&hp_lds[k0 * 260 + h];
            float4 p1 = *(float4*)&hp_lds[k1 * 260 + h];
            float4 wv = *(float4*)&wc2s[h];
            s0 += fmaxf(p0.x + f0, 0.f) * wv.x;
            s0 += fmaxf(p0.y + f1, 0.f) * wv.y;
            s0 += fmaxf(p0.z + f2, 0.f) * wv.z;
            s0 += fmaxf(p0.w + f3, 0.f) * wv.w;
            s1 += fmaxf(p1.x + f0, 0.f) * wv.x;
            s1 += fmaxf(p1.y + f1, 0.f) * wv.y;
            s1 += fmaxf(p1.z + f2, 0.f) * wv.z;
            s1 += fmaxf(p1.w + f3, 0.f) * wv.w;
        }
        float bc2 = bc2p[0];
        float v0 = 1.f / (1.f + __expf(-(s0 + bc2)));
        float v1 = 1.f / (1.f + __expf(-(s1 + bc2)));
        atomicAdd(&confl[k0], v0);
        atomicAdd(&confl[k1], v1);
        __syncthreads();
        if (tid < 32) atomicAdd(&dout[16384 + tid], confl[tid] * (1.0f / 16384.0f));
    }
}

extern "C" void kernel_launch(void* const* d_in, const int* in_sizes, int n_in,
                              void* d_out, int out_size, void* d_ws, size_t ws_size,
                              hipStream_t stream) {
    const float* proto = (const float*)d_in[0];
    const float* qf    = (const float*)d_in[1];
    const float* qd    = (const float*)d_in[2];
    const float* W1    = (const float*)d_in[3];
    const float* b1    = (const float*)d_in[4];
    const float* W2    = (const float*)d_in[5];
    const float* b2    = (const float*)d_in[6];
    const float* Wc1   = (const float*)d_in[7];
    const float* bc1   = (const float*)d_in[8];
    const float* Wc2   = (const float*)d_in[9];
    const float* bc2   = (const float*)d_in[10];
    float* out = (float*)d_out;

    float* ws = (float*)d_ws;
    short* softT   = (short*)ws;                 // 1,572,864 s = 786,432 f
    short* qf2b    = (short*)(ws + 786432);      // 8,388,608 s = 4,194,304 f
    float* wmean   = ws + 4980736;               // 49,152 f (accumulator)
    float* refined = ws + 5029888;               // 16,384 f
    short* hb      = (short*)(ws + 5046272);     // 16,384 s = 8,192 f
    short* W1p     = (short*)(ws + 5054464);     // 524,288 s = 262,144 f
    short* W2p     = (short*)(ws + 5316608);     // 262,144 s = 131,072 f
    short* wqp     = (short*)(ws + 5447680);     // 131,072 s = 65,536 f
    float* hpb     = ws + 5513216;               // 8,192 f
    int*   bar     = (int*)(ws + 5521408);       // 8 ints
    short* hq      = (short*)(ws + 5521416);     // 4,194,304 s = 2,097,152 f (total ~30.5 MB)

    k_A<<<12096, 256, 0, stream>>>(qd, W1, W2, Wc1, proto, qf, softT, W1p, W2p, wqp,
                                   refined, qf2b, wmean, bar, out);
    k_B<<<512, 256, 0, stream>>>(qf2b, softT, wqp, wmean, hq);
    k_C<<<128, 256, 0, stream>>>(softT, wmean, proto, Wc1, bc1, hpb);
    k_D<<<1040, 256, 0, stream>>>(wmean, W1p, b1, W2p, b2, refined, hb, bar,
                                  hq, hpb, Wc2, bc2, out);
}